// Round 1
// baseline (257.055 us; speedup 1.0000x reference)
//
#include <hip/hip_runtime.h>

// Problem constants (SpatioConvLayer): B=16, C_IN=C_OUT=64, T=12, N=1024, KS=3
#define NB   16
#define NC   64
#define NT   12
#define NN   1024
#define NKS  3

typedef float  f32x4  __attribute__((ext_vector_type(4)));
typedef short  s16x8  __attribute__((ext_vector_type(8)));
typedef unsigned short u16x4 __attribute__((ext_vector_type(4)));

__device__ __forceinline__ unsigned short f2bf(float f) {
    union { float f; unsigned u; } v; v.f = f;
    unsigned r = v.u + 0x7FFFu + ((v.u >> 16) & 1u);   // round-to-nearest-even
    return (unsigned short)(r >> 16);
}

// LDS layout (51200 B total, aliased across phases):
//   phase 1 (K-loop staging): As[128][40] u16 @0 (10240 B), Bs[192][40] u16 @10240 (15360 B)
//   phase 2 (theta stage):    thS[64][200] u16 @0 (25600 B), xmT[64][200] u16 @25600 (25600 B)
#define SMEM_BYTES 51200

__global__ __launch_bounds__(256, 2)
void spatio_fused(const float* __restrict__ x, const float* __restrict__ kern,
                  const float* __restrict__ theta, const float* __restrict__ bias,
                  float* __restrict__ out)
{
    __shared__ __attribute__((aligned(128))) char smem[SMEM_BYTES];
    unsigned short (*As)[40]  = (unsigned short (*)[40])(smem);
    unsigned short (*Bs)[40]  = (unsigned short (*)[40])(smem + 10240);
    unsigned short (*thS)[200] = (unsigned short (*)[200])(smem);
    unsigned short (*xmT)[200] = (unsigned short (*)[200])(smem + 25600);

    const int tid  = threadIdx.x;
    const int g    = blockIdx.x;          // bt-pair index 0..95
    const int mt   = blockIdx.y;          // m-tile 0..15
    const int m_base = mt * 64;
    const int lane = tid & 63;
    const int wid  = tid >> 6;            // 0..3
    const int wm   = wid & 1;             // row half = bt_local
    const int wn   = wid >> 1;            // col half (96 cols each)
    const int quad = lane >> 4;
    const int l16  = lane & 15;

    // ---- A-staging: each thread owns one row R (bt_local, c) and half its 32 n's
    const int R    = tid >> 1;            // 0..127
    const int btlA = R >> 6;
    const int cA   = R & 63;
    const int btA  = 2 * g + btlA;
    const int bA   = btA / NT, tA = btA % NT;
    const float* xrow = x + (((size_t)(bA * NC + cA) * NT + tA) * NN);
    const int nn0 = (tid & 1) * 16;

    f32x4 acc[4][6];
#pragma unroll
    for (int i = 0; i < 4; ++i)
#pragma unroll
        for (int j = 0; j < 6; ++j) acc[i][j] = (f32x4){0.f, 0.f, 0.f, 0.f};

    // ================= stage 1: xm = x @ K  (K-loop over n) =================
    for (int n0 = 0; n0 < NN; n0 += 32) {
        __syncthreads();   // protect LDS from previous iteration's frag reads
        // A tile: 128 rows x 32 n (f32 -> bf16)
        {
            const float4* src = (const float4*)(xrow + n0 + nn0);
#pragma unroll
            for (int q4 = 0; q4 < 4; ++q4) {
                float4 v = src[q4];
                u16x4 w;
                w.x = f2bf(v.x); w.y = f2bf(v.y); w.z = f2bf(v.z); w.w = f2bf(v.w);
                *(u16x4*)&As[R][nn0 + 4 * q4] = w;
            }
        }
        // B tile (transposed store): Bs[j][nn], j = k*64+mm, 32 n-rows
#pragma unroll
        for (int p = 0; p < 12; ++p) {
            int item = tid + 256 * p;          // 0..3071
            int j    = item % 192;
            int nn2  = item / 192;             // 0..15 (pair of n rows)
            int gcol = ((j >> 6) << 10) + m_base + (j & 63);
            const float* kp = kern + ((size_t)(n0 + 2 * nn2) * (NKS * NN)) + gcol;
            float v0 = kp[0];
            float v1 = kp[NKS * NN];
            unsigned pack = (unsigned)f2bf(v0) | ((unsigned)f2bf(v1) << 16);
            *(unsigned*)&Bs[j][2 * nn2] = pack;
        }
        __syncthreads();
        // fragments + MFMA: wave tile 64 rows x 96 cols
        s16x8 afr[4], bfr[6];
#pragma unroll
        for (int i = 0; i < 4; ++i)
            afr[i] = *(const s16x8*)&As[64 * wm + 16 * i + l16][quad * 8];
#pragma unroll
        for (int j = 0; j < 6; ++j)
            bfr[j] = *(const s16x8*)&Bs[96 * wn + 16 * j + l16][quad * 8];
#pragma unroll
        for (int i = 0; i < 4; ++i)
#pragma unroll
            for (int j = 0; j < 6; ++j)
                acc[i][j] = __builtin_amdgcn_mfma_f32_16x16x32_bf16(afr[i], bfr[j], acc[i][j], 0, 0, 0);
    }

    __syncthreads();   // all frag reads done; As/Bs now dead

    // ---- theta -> thS[o][ck], ck = k*64 + c  (A-operand layout for stage 2)
#pragma unroll
    for (int p = 0; p < 48; ++p) {
        int item = tid + 256 * p;      // 0..12287
        int o = item & 63;
        int r = item >> 6;             // 0..191 = c*3 + k
        int c = r / 3;
        int k = r - 3 * c;
        thS[o][k * 64 + c] = f2bf(theta[item]);
    }

    // ================= stage 2: gc = th^T @ xm, one bt per pass =================
    for (int pass = 0; pass < 2; ++pass) {
        __syncthreads();               // thS ready / previous pass reads done
        if (wm == pass) {
            // write this wave's accumulators into xmT[mm][ck] (B-operand layout)
#pragma unroll
            for (int i = 0; i < 4; ++i)
#pragma unroll
                for (int j = 0; j < 6; ++j) {
                    int J  = 96 * wn + 16 * j + l16;
                    int kk = J >> 6, mm = J & 63;
                    int ck0 = kk * 64 + 16 * i + 4 * quad;   // c = 16i + 4*quad + reg
                    u16x4 w;
                    w.x = f2bf(acc[i][j].x); w.y = f2bf(acc[i][j].y);
                    w.z = f2bf(acc[i][j].z); w.w = f2bf(acc[i][j].w);
                    *(u16x4*)&xmT[mm][ck0] = w;
                }
        }
        __syncthreads();

        f32x4 acc2[4];
#pragma unroll
        for (int j = 0; j < 4; ++j) acc2[j] = (f32x4){0.f, 0.f, 0.f, 0.f};
#pragma unroll
        for (int ks = 0; ks < 6; ++ks) {       // K = 192 = 6 x 32
            s16x8 a2 = *(const s16x8*)&thS[16 * wid + l16][ks * 32 + quad * 8];
#pragma unroll
            for (int j = 0; j < 4; ++j) {
                s16x8 b2 = *(const s16x8*)&xmT[16 * j + l16][ks * 32 + quad * 8];
                acc2[j] = __builtin_amdgcn_mfma_f32_16x16x32_bf16(a2, b2, acc2[j], 0, 0, 0);
            }
        }

        // epilogue: out = relu(gc + bias + x), residual at channel o
        const int bt = 2 * g + pass;
        const int bb = bt / NT, tt = bt % NT;
#pragma unroll
        for (int j = 0; j < 4; ++j) {
            int mm = 16 * j + l16;
#pragma unroll
            for (int r = 0; r < 4; ++r) {
                int o = 16 * wid + 4 * quad + r;
                size_t idx = (((size_t)(bb * NC + o) * NT + tt) * NN) + m_base + mm;
                float v = acc2[j][r] + bias[o] + x[idx];
                out[idx] = fmaxf(v, 0.f);
            }
        }
    }
}

extern "C" void kernel_launch(void* const* d_in, const int* in_sizes, int n_in,
                              void* d_out, int out_size, void* d_ws, size_t ws_size,
                              hipStream_t stream) {
    const float* x     = (const float*)d_in[0];
    const float* kern  = (const float*)d_in[1];
    const float* theta = (const float*)d_in[2];
    const float* bias  = (const float*)d_in[3];
    float* out = (float*)d_out;
    (void)in_sizes; (void)n_in; (void)out_size; (void)d_ws; (void)ws_size;
    dim3 grid(96, 16, 1);
    dim3 block(256, 1, 1);
    hipLaunchKernelGGL(spatio_fused, grid, block, 0, stream, x, kern, theta, bias, out);
}